// Round 1
// baseline (3129.284 us; speedup 1.0000x reference)
//
#include <hip/hip_runtime.h>
#include <hip/hip_bf16.h>

typedef short bf16x8 __attribute__((ext_vector_type(8)));
typedef float f32x4 __attribute__((ext_vector_type(4)));

typedef __attribute__((address_space(1))) void gvoid;
typedef __attribute__((address_space(3))) void lvoid;

__device__ __forceinline__ short f2b(float f) {
  __hip_bfloat16 h = __float2bfloat16(f);
  return __builtin_bit_cast(short, h);
}

__device__ __forceinline__ f32x4 mfma16(bf16x8 a, bf16x8 b, f32x4 c) {
  return __builtin_amdgcn_mfma_f32_16x16x32_bf16(a, b, c, 0, 0, 0);
}

__device__ __forceinline__ void gload16(const void* g, void* l) {
  __builtin_amdgcn_global_load_lds((const gvoid*)g, (lvoid*)l, 16, 0, 0);
}

// ---------------------------------------------------------------- weights
__global__ __launch_bounds__(256) void convT_k(const float* __restrict__ src,
                                               short* __restrict__ dst, int K,
                                               int N, int scale_cols,
                                               float scale) {
  int idx = blockIdx.x * 256 + threadIdx.x;
  if (idx >= N * K) return;
  int n = idx / K, k = idx % K;
  float v = src[(size_t)k * N + n];
  if (n < scale_cols) v *= scale;
  dst[idx] = f2b(v);
}

__global__ __launch_bounds__(256) void scale_bias_k(const float* __restrict__ src,
                                                    float* __restrict__ dst,
                                                    int n, int scale_cols,
                                                    float scale) {
  int i = blockIdx.x * 256 + threadIdx.x;
  if (i >= n) return;
  dst[i] = src[i] * (i < scale_cols ? scale : 1.f);
}

// ---------------------------------------------------------------- layernorm
// GATHER: fused cyclic shift (-3,-3) + window partition into token order
// (b, wh, ww, i, j). Output bf16.
template <bool GATHER>
__global__ __launch_bounds__(256) void ln_k(const float* __restrict__ x,
                                            const float* __restrict__ gw,
                                            const float* __restrict__ bw,
                                            short* __restrict__ out) {
  const int lane = threadIdx.x & 63;
  const int t = (blockIdx.x << 2) + (threadIdx.x >> 6);
  size_t srow;
  if (GATHER) {
    int bb = t / 12544, rm2 = t % 12544;
    int wi = rm2 / 49, nn = rm2 % 49;
    int wh = wi >> 4, ww = wi & 15;
    int ii = nn / 7, jj = nn % 7;
    int rr = wh * 7 + ii + 3; if (rr >= 112) rr -= 112;
    int cc = ww * 7 + jj + 3; if (cc >= 112) cc -= 112;
    srow = ((size_t)bb * 12544 + rr * 112 + cc) * 384;
  } else {
    srow = (size_t)t * 384;
  }
  const float* src = x + srow;
  float v[6], s = 0.f, ss = 0.f;
#pragma unroll
  for (int k = 0; k < 6; ++k) {
    v[k] = src[lane + (k << 6)];
    s += v[k];
    ss += v[k] * v[k];
  }
#pragma unroll
  for (int m = 1; m < 64; m <<= 1) {
    s += __shfl_xor(s, m, 64);
    ss += __shfl_xor(ss, m, 64);
  }
  const float mean = s * (1.f / 384.f);
  const float var = ss * (1.f / 384.f) - mean * mean;
  const float rstd = rsqrtf(var + 1e-5f);
  short* o = out + (size_t)t * 384;
#pragma unroll
  for (int k = 0; k < 6; ++k) {
    int c = lane + (k << 6);
    o[c] = f2b((v[k] - mean) * rstd * gw[c] + bw[c]);
  }
}

// ---------------------------------------------------------------- GEMM
// C[M,N] = A[M,K] * BT[N,K]^T + bias. 128x128 tile, BK=32, 4 waves (2x2),
// each wave 4x4 fragments of 16x16x32 MFMA. global_load_lds width-16 staging.
// EPI 0: bias -> bf16 out            (qkv)
// EPI 1: bias+GELU(erf) -> bf16 out  (fc1)
// EPI 2: bias + window-reverse/roll scatter + residual(x) -> fp32 (proj)
// EPI 3: bias(opt) + accumulate into fp32 out               (fc2 chunks)
template <int EPI>
__global__ __launch_bounds__(256) void gemm_k(
    const short* __restrict__ A, int lda, const short* __restrict__ BT,
    int ldb, const float* __restrict__ bias, int K, short* __restrict__ outh,
    int ldo, float* __restrict__ outf, const float* __restrict__ resid) {
  __shared__ short As[128 * 32];
  __shared__ short Bs[128 * 32];
  const int tid = threadIdx.x;
  const int m0 = blockIdx.y << 7, n0 = blockIdx.x << 7;
  const int lane = tid & 63;
  const int wave = tid >> 6;
  const int wr = (wave >> 1) << 6, wc = (wave & 1) << 6;
  const int g = lane >> 4, q = lane & 15;
  const int srow = tid >> 2, sch = (tid & 3) << 3;

  f32x4 acc[4][4];
#pragma unroll
  for (int i = 0; i < 4; ++i)
#pragma unroll
    for (int j = 0; j < 4; ++j) acc[i][j] = (f32x4){0.f, 0.f, 0.f, 0.f};

  const short* Ab = A + (size_t)(m0 + srow) * lda + sch;
  const short* Bb = BT + (size_t)(n0 + srow) * ldb + sch;
  short* Al0 = &As[srow * 32 + sch];
  short* Al1 = &As[(srow + 64) * 32 + sch];
  short* Bl0 = &Bs[srow * 32 + sch];
  short* Bl1 = &Bs[(srow + 64) * 32 + sch];

  for (int kt = 0; kt < K; kt += 32) {
    __syncthreads();
    gload16(Ab + kt, Al0);
    gload16(Ab + (size_t)64 * lda + kt, Al1);
    gload16(Bb + kt, Bl0);
    gload16(Bb + (size_t)64 * ldb + kt, Bl1);
    __syncthreads();
    bf16x8 af[4], bfv[4];
#pragma unroll
    for (int mi = 0; mi < 4; ++mi)
      af[mi] = *(const bf16x8*)&As[(wr + mi * 16 + q) * 32 + g * 8];
#pragma unroll
    for (int ni = 0; ni < 4; ++ni)
      bfv[ni] = *(const bf16x8*)&Bs[(wc + ni * 16 + q) * 32 + g * 8];
#pragma unroll
    for (int mi = 0; mi < 4; ++mi)
#pragma unroll
      for (int ni = 0; ni < 4; ++ni)
        acc[mi][ni] = mfma16(af[mi], bfv[ni], acc[mi][ni]);
  }

#pragma unroll
  for (int mi = 0; mi < 4; ++mi) {
#pragma unroll
    for (int r = 0; r < 4; ++r) {
      const int grow = m0 + wr + mi * 16 + g * 4 + r;
      size_t orow;
      if constexpr (EPI == 2) {
        int bb = grow / 12544, rm2 = grow % 12544;
        int wi = rm2 / 49, nn = rm2 % 49;
        int wh = wi >> 4, ww = wi & 15;
        int ii = nn / 7, jj = nn % 7;
        int rr = wh * 7 + ii + 3; if (rr >= 112) rr -= 112;
        int cc = ww * 7 + jj + 3; if (cc >= 112) cc -= 112;
        orow = ((size_t)bb * 12544 + rr * 112 + cc) * 384;
      } else {
        orow = (size_t)grow * (size_t)ldo;
      }
#pragma unroll
      for (int ni = 0; ni < 4; ++ni) {
        const int gcol = n0 + wc + ni * 16 + q;
        float v = acc[mi][ni][r];
        if (bias) v += bias[gcol];
        if constexpr (EPI == 0) {
          outh[orow + gcol] = f2b(v);
        } else if constexpr (EPI == 1) {
          v = 0.5f * v * (1.f + erff(v * 0.70710678118f));
          outh[orow + gcol] = f2b(v);
        } else if constexpr (EPI == 2) {
          outf[orow + gcol] = resid[orow + gcol] + v;
        } else {
          outf[orow + gcol] += v;
        }
      }
    }
  }
}

// ---------------------------------------------------------------- attention
// One wave per (window, head). N=49 padded to 64. qkv layout: row = token
// (win*49+n), cols = s*384 + h*32 + d. Q pre-scaled via folded weights.
__global__ __launch_bounds__(64) void attn_k(const short* __restrict__ qkv,
                                             const float* __restrict__ rpb,
                                             short* __restrict__ out) {
  __shared__ short P[64 * 64];
  __shared__ short Vt[32 * 64];
  const int lane = threadIdx.x;
  const int g = lane >> 4, q = lane & 15;
  const int h = blockIdx.x;
  const int win = blockIdx.y;
  const int wh = (win >> 4) & 15, ww = win & 15;
  const size_t tokbase = (size_t)win * 49;
  const bf16x8 zero8 = {0, 0, 0, 0, 0, 0, 0, 0};

  // Q,K fragments directly from global (A-frag pattern: row=q, k=8g+e)
  bf16x8 qf[4], kf[4];
#pragma unroll
  for (int t = 0; t < 4; ++t) {
    int r = t * 16 + q;
    bool ok = r < 49;
    size_t off = (tokbase + (ok ? r : 0)) * 1152 + h * 32 + g * 8;
    bf16x8 a = *(const bf16x8*)(qkv + off);
    bf16x8 b = *(const bf16x8*)(qkv + off + 384);
    qf[t] = ok ? a : zero8;
    kf[t] = ok ? b : zero8;
  }
  f32x4 s[4][4];
#pragma unroll
  for (int mi = 0; mi < 4; ++mi)
#pragma unroll
    for (int ni = 0; ni < 4; ++ni)
      s[mi][ni] = mfma16(qf[mi], kf[ni], (f32x4){0.f, 0.f, 0.f, 0.f});

  // stage V transposed: Vt[d][k], zero pad rows k>=49
#pragma unroll
  for (int p = 0; p < 4; ++p) {
    int r = (p << 4) + (lane >> 2);
    int dch = (lane & 3) << 3;
    bf16x8 vv = zero8;
    if (r < 49)
      vv = *(const bf16x8*)(qkv + (tokbase + r) * 1152 + 768 + h * 32 + dch);
#pragma unroll
    for (int e = 0; e < 8; ++e) Vt[(dch + e) * 64 + r] = vv[e];
  }

  // rel-pos bias + shift mask (computed arithmetically)
  int m4[4], i2[4], j2[4], creg[4];
#pragma unroll
  for (int ni = 0; ni < 4; ++ni) {
    m4[ni] = ni * 16 + q;
    int mc = m4[ni] < 49 ? m4[ni] : 48;
    i2[ni] = mc / 7;
    j2[ni] = mc % 7;
    int rr = wh * 7 + i2[ni], cc = ww * 7 + j2[ni];
    creg[ni] = ((rr >= 105) + (rr >= 109)) * 3 + (cc >= 105) + (cc >= 109);
  }
#pragma unroll
  for (int mi = 0; mi < 4; ++mi) {
#pragma unroll
    for (int r = 0; r < 4; ++r) {
      int n = mi * 16 + g * 4 + r;
      int nc = n < 49 ? n : 48;
      int i1 = nc / 7, j1 = nc % 7;
      int rr = wh * 7 + i1, cc = ww * 7 + j1;
      int rreg = ((rr >= 105) + (rr >= 109)) * 3 + (cc >= 105) + (cc >= 109);
#pragma unroll
      for (int ni = 0; ni < 4; ++ni) {
        float sv = s[mi][ni][r];
        sv += rpb[(size_t)((i1 - i2[ni] + 6) * 13 + (j1 - j2[ni] + 6)) * 12 + h];
        if (rreg != creg[ni]) sv -= 100.f;
        if (m4[ni] >= 49) sv = -1e30f;
        s[mi][ni][r] = sv;
      }
    }
  }
  // row softmax: reduce over 4 in-lane cols + 16 lanes of the group
#pragma unroll
  for (int mi = 0; mi < 4; ++mi) {
#pragma unroll
    for (int r = 0; r < 4; ++r) {
      float mx = s[mi][0][r];
#pragma unroll
      for (int ni = 1; ni < 4; ++ni) mx = fmaxf(mx, s[mi][ni][r]);
#pragma unroll
      for (int m = 1; m < 16; m <<= 1) mx = fmaxf(mx, __shfl_xor(mx, m, 64));
      float sm = 0.f;
#pragma unroll
      for (int ni = 0; ni < 4; ++ni) {
        float e = expf(s[mi][ni][r] - mx);
        s[mi][ni][r] = e;
        sm += e;
      }
#pragma unroll
      for (int m = 1; m < 16; m <<= 1) sm += __shfl_xor(sm, m, 64);
      float rinv = 1.f / sm;
#pragma unroll
      for (int ni = 0; ni < 4; ++ni)
        P[(mi * 16 + g * 4 + r) * 64 + ni * 16 + q] = f2b(s[mi][ni][r] * rinv);
    }
  }
  __syncthreads();

  // PV: P(64x64) @ V(64x32)
  f32x4 o[4][2];
#pragma unroll
  for (int mi = 0; mi < 4; ++mi)
#pragma unroll
    for (int di = 0; di < 2; ++di) o[mi][di] = (f32x4){0.f, 0.f, 0.f, 0.f};
#pragma unroll
  for (int kt = 0; kt < 2; ++kt) {
    bf16x8 pa[4], vb[2];
#pragma unroll
    for (int mi = 0; mi < 4; ++mi)
      pa[mi] = *(const bf16x8*)&P[(mi * 16 + q) * 64 + kt * 32 + g * 8];
#pragma unroll
    for (int di = 0; di < 2; ++di)
      vb[di] = *(const bf16x8*)&Vt[(di * 16 + q) * 64 + kt * 32 + g * 8];
#pragma unroll
    for (int mi = 0; mi < 4; ++mi)
#pragma unroll
      for (int di = 0; di < 2; ++di)
        o[mi][di] = mfma16(pa[mi], vb[di], o[mi][di]);
  }
#pragma unroll
  for (int mi = 0; mi < 4; ++mi)
#pragma unroll
    for (int di = 0; di < 2; ++di)
#pragma unroll
      for (int r = 0; r < 4; ++r) {
        int n = mi * 16 + g * 4 + r;
        if (n < 49)
          out[(tokbase + n) * 384 + h * 32 + di * 16 + q] = f2b(o[mi][di][r]);
      }
}

// ---------------------------------------------------------------- launch
extern "C" void kernel_launch(void* const* d_in, const int* in_sizes, int n_in,
                              void* d_out, int out_size, void* d_ws,
                              size_t ws_size, hipStream_t stream) {
  const float* x = (const float*)d_in[0];
  const float* n1g = (const float*)d_in[1];
  const float* n1b = (const float*)d_in[2];
  const float* qkvw = (const float*)d_in[3];
  const float* qkvb = (const float*)d_in[4];
  const float* projw = (const float*)d_in[5];
  const float* projb = (const float*)d_in[6];
  const float* rpb = (const float*)d_in[7];
  const float* n2g = (const float*)d_in[8];
  const float* n2b = (const float*)d_in[9];
  const float* fc1w = (const float*)d_in[10];
  const float* fc1b = (const float*)d_in[11];
  const float* fc2w = (const float*)d_in[12];
  const float* fc2b = (const float*)d_in[13];
  float* out = (float*)d_out;

  char* ws = (char*)d_ws;
  short* w_qkvT = (short*)(ws + 0);                   // 1152x384 bf16 = 884736 B
  short* w_projT = (short*)(ws + 884736);             // 384x384       = 294912 B
  short* w_fc1T = (short*)(ws + 1179648);             // 1536x384      = 1179648 B
  short* w_fc2T = (short*)(ws + 2359296);             // 384x1536      = 1179648 B
  float* w_qb = (float*)(ws + 3538944);               // 1152 f32      = 4608 B
  const size_t o_qkv = 3543552;
  short* qkvbuf = (short*)(ws + o_qkv);               // 200704x1152 bf16
  const size_t o_hwin = o_qkv + 462422016ull;
  short* hwin = (short*)(ws + o_hwin);                // 200704x384 bf16 (later attn_out)
  const size_t o_fc1 = o_hwin + 154140672ull;

  int NC;
  size_t fc1_off = o_fc1;
  if (ws_size >= o_fc1 + 616562688ull) NC = 1;
  else if (ws_size >= o_fc1 + 308281344ull) NC = 2;
  else if (ws_size >= o_fc1 + 154140672ull) NC = 4;
  else { NC = 4; fc1_off = o_hwin; }  // overlay on hwin (dead after proj)
  short* fc1c = (short*)(ws + fc1_off);
  short* h2 = qkvbuf;  // reuse qkv region for LN2 output

  const float qscale = 0.17677669529663687f;  // 32^-0.5 folded into Q weights

  convT_k<<<(442368 + 255) / 256, 256, 0, stream>>>(qkvw, w_qkvT, 384, 1152, 384, qscale);
  convT_k<<<(147456 + 255) / 256, 256, 0, stream>>>(projw, w_projT, 384, 384, 0, 1.f);
  convT_k<<<(589824 + 255) / 256, 256, 0, stream>>>(fc1w, w_fc1T, 384, 1536, 0, 1.f);
  convT_k<<<(589824 + 255) / 256, 256, 0, stream>>>(fc2w, w_fc2T, 1536, 384, 0, 1.f);
  scale_bias_k<<<5, 256, 0, stream>>>(qkvb, w_qb, 1152, 384, qscale);

  // LN1 + shift + window partition
  ln_k<true><<<50176, 256, 0, stream>>>(x, n1g, n1b, hwin);
  // QKV
  gemm_k<0><<<dim3(9, 1568), 256, 0, stream>>>(hwin, 384, w_qkvT, 384, w_qb,
                                               384, qkvbuf, 1152, nullptr,
                                               nullptr);
  // attention (writes attn_out into hwin buffer)
  attn_k<<<dim3(12, 4096), 64, 0, stream>>>(qkvbuf, rpb, hwin);
  // proj + window reverse + roll + residual -> d_out (= x_new, fp32)
  gemm_k<2><<<dim3(3, 1568), 256, 0, stream>>>(hwin, 384, w_projT, 384, projb,
                                               384, nullptr, 384, out, x);
  // LN2
  ln_k<false><<<50176, 256, 0, stream>>>(out, n2g, n2b, h2);
  // MLP, chunked over hidden dim
  const int CK = 1536 / NC;
  for (int c = 0; c < NC; ++c) {
    gemm_k<1><<<dim3(CK >> 7, 1568), 256, 0, stream>>>(
        h2, 384, w_fc1T + (size_t)c * CK * 384, 384, fc1b + c * CK, 384, fc1c,
        CK, nullptr, nullptr);
    gemm_k<3><<<dim3(3, 1568), 256, 0, stream>>>(
        fc1c, CK, w_fc2T + c * CK, 1536, (c == 0) ? fc2b : nullptr, CK,
        nullptr, 384, out, nullptr);
  }
}

// Round 2
// 2985.102 us; speedup vs baseline: 1.0483x; 1.0483x over previous
//
#include <hip/hip_runtime.h>
#include <hip/hip_bf16.h>

typedef short bf16x8 __attribute__((ext_vector_type(8)));
typedef float f32x4 __attribute__((ext_vector_type(4)));

typedef __attribute__((address_space(1))) void gvoid;
typedef __attribute__((address_space(3))) void lvoid;

__device__ __forceinline__ short f2b(float f) {
  __hip_bfloat16 h = __float2bfloat16(f);
  return __builtin_bit_cast(short, h);
}

__device__ __forceinline__ f32x4 mfma16(bf16x8 a, bf16x8 b, f32x4 c) {
  return __builtin_amdgcn_mfma_f32_16x16x32_bf16(a, b, c, 0, 0, 0);
}

__device__ __forceinline__ void gload16(const void* g, void* l) {
  __builtin_amdgcn_global_load_lds((const gvoid*)g, (lvoid*)l, 16, 0, 0);
}

// ---------------------------------------------------------------- weights
__global__ __launch_bounds__(256) void convT_k(const float* __restrict__ src,
                                               short* __restrict__ dst, int K,
                                               int N, int scale_cols,
                                               float scale) {
  int idx = blockIdx.x * 256 + threadIdx.x;
  if (idx >= N * K) return;
  int n = idx / K, k = idx % K;
  float v = src[(size_t)k * N + n];
  if (n < scale_cols) v *= scale;
  dst[idx] = f2b(v);
}

__global__ __launch_bounds__(256) void scale_bias_k(const float* __restrict__ src,
                                                    float* __restrict__ dst,
                                                    int n, int scale_cols,
                                                    float scale) {
  int i = blockIdx.x * 256 + threadIdx.x;
  if (i >= n) return;
  dst[i] = src[i] * (i < scale_cols ? scale : 1.f);
}

// ---------------------------------------------------------------- layernorm
template <bool GATHER>
__device__ __forceinline__ void ln_body(const float* __restrict__ x,
                                        const float* __restrict__ gw,
                                        const float* __restrict__ bw,
                                        short* __restrict__ out) {
  const int lane = threadIdx.x & 63;
  const int t = (blockIdx.x << 2) + (threadIdx.x >> 6);
  size_t srow;
  if (GATHER) {
    int bb = t / 12544, rm2 = t % 12544;
    int wi = rm2 / 49, nn = rm2 % 49;
    int wh = wi >> 4, ww = wi & 15;
    int ii = nn / 7, jj = nn % 7;
    int rr = wh * 7 + ii + 3; if (rr >= 112) rr -= 112;
    int cc = ww * 7 + jj + 3; if (cc >= 112) cc -= 112;
    srow = ((size_t)bb * 12544 + rr * 112 + cc) * 384;
  } else {
    srow = (size_t)t * 384;
  }
  const float2* src = (const float2*)(x + srow);
  const float2* g2 = (const float2*)gw;
  const float2* b2 = (const float2*)bw;
  float2 u[3];
  float s = 0.f, ss = 0.f;
#pragma unroll
  for (int k = 0; k < 3; ++k) {
    u[k] = src[lane + (k << 6)];
    s += u[k].x + u[k].y;
    ss += u[k].x * u[k].x + u[k].y * u[k].y;
  }
#pragma unroll
  for (int m = 1; m < 64; m <<= 1) {
    s += __shfl_xor(s, m, 64);
    ss += __shfl_xor(ss, m, 64);
  }
  const float mean = s * (1.f / 384.f);
  const float var = ss * (1.f / 384.f) - mean * mean;
  const float rstd = rsqrtf(var + 1e-5f);
  unsigned* o = (unsigned*)(out + (size_t)t * 384);
#pragma unroll
  for (int k = 0; k < 3; ++k) {
    int c = lane + (k << 6);
    float2 gv = g2[c], bv = b2[c];
    unsigned lo = (unsigned short)f2b((u[k].x - mean) * rstd * gv.x + bv.x);
    unsigned hi = (unsigned short)f2b((u[k].y - mean) * rstd * gv.y + bv.y);
    o[c] = lo | (hi << 16);
  }
}

__global__ __launch_bounds__(256) void ln1_k(const float* __restrict__ x,
                                             const float* __restrict__ gw,
                                             const float* __restrict__ bw,
                                             short* __restrict__ out) {
  ln_body<true>(x, gw, bw, out);
}
__global__ __launch_bounds__(256) void ln2_k(const float* __restrict__ x,
                                             const float* __restrict__ gw,
                                             const float* __restrict__ bw,
                                             short* __restrict__ out) {
  ln_body<false>(x, gw, bw, out);
}

// ---------------------------------------------------------------- GEMM
// C[M,N] = A[M,K] * BT[N,K]^T + bias. 128x128 tile, BK=32, 4 waves (2x2),
// double-buffered LDS with prefetch-before-compute (T3-minimum 2-phase),
// XCD-chunked block swizzle (grids all %8==0).
template <int EPI>
__device__ __forceinline__ void gemm_body(
    const short* __restrict__ A, int lda, const short* __restrict__ BT,
    int ldb, const float* __restrict__ bias, int K, short* __restrict__ outh,
    int ldo, float* __restrict__ outf, const float* __restrict__ resid) {
  __shared__ __align__(16) short As[2][4096];
  __shared__ __align__(16) short Bs[2][4096];
  const int tid = threadIdx.x;
  const int gx = gridDim.x;
  int lin = blockIdx.y * gx + blockIdx.x;
  const int cpx = (gx * gridDim.y) >> 3;
  lin = (lin & 7) * cpx + (lin >> 3);
  const int m0 = (lin / gx) << 7, n0 = (lin % gx) << 7;
  const int lane = tid & 63;
  const int wave = tid >> 6;
  const int wr = (wave >> 1) << 6, wc = (wave & 1) << 6;
  const int g = lane >> 4, q = lane & 15;
  const int loff = tid << 3;

  f32x4 acc[4][4];
#pragma unroll
  for (int i = 0; i < 4; ++i)
#pragma unroll
    for (int j = 0; j < 4; ++j) acc[i][j] = (f32x4){0.f, 0.f, 0.f, 0.f};

  const short* Ab = A + (size_t)(m0 + (tid >> 2)) * lda + ((tid & 3) << 3);
  const short* Ab2 = Ab + (size_t)64 * lda;
  const short* Bb = BT + (size_t)(n0 + (tid >> 2)) * ldb + ((tid & 3) << 3);
  const short* Bb2 = Bb + (size_t)64 * ldb;

  // prologue: stage tile 0
  gload16(Ab, &As[0][loff]);
  gload16(Ab2, &As[0][loff + 2048]);
  gload16(Bb, &Bs[0][loff]);
  gload16(Bb2, &Bs[0][loff + 2048]);
  __syncthreads();

  const int nt = K >> 5;
  int cur = 0;
  for (int t = 0; t < nt; ++t) {
    if (t + 1 < nt) {  // prefetch next tile into alternate buffer
      const int kn = (t + 1) << 5;
      short* dA = &As[cur ^ 1][loff];
      short* dB = &Bs[cur ^ 1][loff];
      gload16(Ab + kn, dA);
      gload16(Ab2 + kn, dA + 2048);
      gload16(Bb + kn, dB);
      gload16(Bb2 + kn, dB + 2048);
    }
    bf16x8 af[4], bfv[4];
#pragma unroll
    for (int mi = 0; mi < 4; ++mi)
      af[mi] = *(const bf16x8*)&As[cur][(wr + mi * 16 + q) * 32 + g * 8];
#pragma unroll
    for (int ni = 0; ni < 4; ++ni)
      bfv[ni] = *(const bf16x8*)&Bs[cur][(wc + ni * 16 + q) * 32 + g * 8];
#pragma unroll
    for (int mi = 0; mi < 4; ++mi)
#pragma unroll
      for (int ni = 0; ni < 4; ++ni)
        acc[mi][ni] = mfma16(af[mi], bfv[ni], acc[mi][ni]);
    __syncthreads();
    cur ^= 1;
  }

#pragma unroll
  for (int mi = 0; mi < 4; ++mi) {
#pragma unroll
    for (int r = 0; r < 4; ++r) {
      const int grow = m0 + wr + mi * 16 + g * 4 + r;
      size_t orow;
      if constexpr (EPI == 2) {
        int bb = grow / 12544, rm2 = grow % 12544;
        int wi = rm2 / 49, nn = rm2 % 49;
        int wh = wi >> 4, ww = wi & 15;
        int ii = nn / 7, jj = nn % 7;
        int rr = wh * 7 + ii + 3; if (rr >= 112) rr -= 112;
        int cc = ww * 7 + jj + 3; if (cc >= 112) cc -= 112;
        orow = ((size_t)bb * 12544 + rr * 112 + cc) * 384;
      } else {
        orow = (size_t)grow * (size_t)ldo;
      }
#pragma unroll
      for (int ni = 0; ni < 4; ++ni) {
        const int gcol = n0 + wc + ni * 16 + q;
        float v = acc[mi][ni][r];
        if (bias) v += bias[gcol];
        if constexpr (EPI == 0) {
          outh[orow + gcol] = f2b(v);
        } else if constexpr (EPI == 1) {
          v = 0.5f * v * (1.f + erff(v * 0.70710678118f));
          outh[orow + gcol] = f2b(v);
        } else if constexpr (EPI == 2) {
          outf[orow + gcol] = resid[orow + gcol] + v;
        } else {
          outf[orow + gcol] += v;
        }
      }
    }
  }
}

#define GEMM_WRAP(NAME, EPI)                                                   \
  __global__ __launch_bounds__(256) void NAME(                                 \
      const short* __restrict__ A, int lda, const short* __restrict__ BT,      \
      int ldb, const float* __restrict__ bias, int K,                          \
      short* __restrict__ outh, int ldo, float* __restrict__ outf,             \
      const float* __restrict__ resid) {                                       \
    gemm_body<EPI>(A, lda, BT, ldb, bias, K, outh, ldo, outf, resid);          \
  }
GEMM_WRAP(gemm_qkv_k, 0)
GEMM_WRAP(gemm_fc1_k, 1)
GEMM_WRAP(gemm_proj_k, 2)
GEMM_WRAP(gemm_fc2_k, 3)

// ---------------------------------------------------------------- attention
// One wave per (window, head). N=49 padded to 64. P and Vt are XOR-swizzled
// (row&7)<<3 on the short index to break the 128B-row-stride bank conflict.
#define SW(row, sidx) ((sidx) ^ (((row)&7) << 3))

__global__ __launch_bounds__(64) void attn_k(const short* __restrict__ qkv,
                                             const float* __restrict__ rpb,
                                             short* __restrict__ out) {
  __shared__ __align__(16) short P[64 * 64];
  __shared__ __align__(16) short Vt[32 * 64];
  const int lane = threadIdx.x;
  const int g = lane >> 4, q = lane & 15;
  const int h = blockIdx.x;
  const int win = blockIdx.y;
  const int wh = (win >> 4) & 15, ww = win & 15;
  const size_t tokbase = (size_t)win * 49;
  const bf16x8 zero8 = {0, 0, 0, 0, 0, 0, 0, 0};

  bf16x8 qf[4], kf[4];
#pragma unroll
  for (int t = 0; t < 4; ++t) {
    int r = t * 16 + q;
    bool ok = r < 49;
    size_t off = (tokbase + (ok ? r : 0)) * 1152 + h * 32 + g * 8;
    bf16x8 a = *(const bf16x8*)(qkv + off);
    bf16x8 b = *(const bf16x8*)(qkv + off + 384);
    qf[t] = ok ? a : zero8;
    kf[t] = ok ? b : zero8;
  }
  f32x4 s[4][4];
#pragma unroll
  for (int mi = 0; mi < 4; ++mi)
#pragma unroll
    for (int ni = 0; ni < 4; ++ni)
      s[mi][ni] = mfma16(qf[mi], kf[ni], (f32x4){0.f, 0.f, 0.f, 0.f});

  // stage V transposed (swizzled): Vt[d][k]
#pragma unroll
  for (int p = 0; p < 4; ++p) {
    int r = (p << 4) + (lane >> 2);
    int dch = (lane & 3) << 3;
    bf16x8 vv = zero8;
    if (r < 49)
      vv = *(const bf16x8*)(qkv + (tokbase + r) * 1152 + 768 + h * 32 + dch);
#pragma unroll
    for (int e = 0; e < 8; ++e) {
      int d = dch + e;
      Vt[SW(d, d * 64 + r)] = vv[e];
    }
  }

  int m4[4], i2[4], j2[4], creg[4];
#pragma unroll
  for (int ni = 0; ni < 4; ++ni) {
    m4[ni] = ni * 16 + q;
    int mc = m4[ni] < 49 ? m4[ni] : 48;
    i2[ni] = mc / 7;
    j2[ni] = mc % 7;
    int rr = wh * 7 + i2[ni], cc = ww * 7 + j2[ni];
    creg[ni] = ((rr >= 105) + (rr >= 109)) * 3 + (cc >= 105) + (cc >= 109);
  }
#pragma unroll
  for (int mi = 0; mi < 4; ++mi) {
#pragma unroll
    for (int r = 0; r < 4; ++r) {
      int n = mi * 16 + g * 4 + r;
      int nc = n < 49 ? n : 48;
      int i1 = nc / 7, j1 = nc % 7;
      int rr = wh * 7 + i1, cc = ww * 7 + j1;
      int rreg = ((rr >= 105) + (rr >= 109)) * 3 + (cc >= 105) + (cc >= 109);
#pragma unroll
      for (int ni = 0; ni < 4; ++ni) {
        float sv = s[mi][ni][r];
        sv += rpb[(size_t)((i1 - i2[ni] + 6) * 13 + (j1 - j2[ni] + 6)) * 12 + h];
        if (rreg != creg[ni]) sv -= 100.f;
        if (m4[ni] >= 49) sv = -1e30f;
        s[mi][ni][r] = sv;
      }
    }
  }
#pragma unroll
  for (int mi = 0; mi < 4; ++mi) {
#pragma unroll
    for (int r = 0; r < 4; ++r) {
      float mx = s[mi][0][r];
#pragma unroll
      for (int ni = 1; ni < 4; ++ni) mx = fmaxf(mx, s[mi][ni][r]);
#pragma unroll
      for (int m = 1; m < 16; m <<= 1) mx = fmaxf(mx, __shfl_xor(mx, m, 64));
      float sm = 0.f;
#pragma unroll
      for (int ni = 0; ni < 4; ++ni) {
        float e = __expf(s[mi][ni][r] - mx);
        s[mi][ni][r] = e;
        sm += e;
      }
#pragma unroll
      for (int m = 1; m < 16; m <<= 1) sm += __shfl_xor(sm, m, 64);
      float rinv = 1.f / sm;
      int row = mi * 16 + g * 4 + r;
#pragma unroll
      for (int ni = 0; ni < 4; ++ni)
        P[SW(row, row * 64 + ni * 16 + q)] = f2b(s[mi][ni][r] * rinv);
    }
  }
  __syncthreads();

  f32x4 o[4][2];
#pragma unroll
  for (int mi = 0; mi < 4; ++mi)
#pragma unroll
    for (int di = 0; di < 2; ++di) o[mi][di] = (f32x4){0.f, 0.f, 0.f, 0.f};
#pragma unroll
  for (int kt = 0; kt < 2; ++kt) {
    bf16x8 pa[4], vb[2];
#pragma unroll
    for (int mi = 0; mi < 4; ++mi) {
      int row = mi * 16 + q;
      pa[mi] = *(const bf16x8*)&P[SW(row, row * 64 + kt * 32 + g * 8)];
    }
#pragma unroll
    for (int di = 0; di < 2; ++di) {
      int row = di * 16 + q;
      vb[di] = *(const bf16x8*)&Vt[SW(row, row * 64 + kt * 32 + g * 8)];
    }
#pragma unroll
    for (int mi = 0; mi < 4; ++mi)
#pragma unroll
      for (int di = 0; di < 2; ++di)
        o[mi][di] = mfma16(pa[mi], vb[di], o[mi][di]);
  }
#pragma unroll
  for (int mi = 0; mi < 4; ++mi)
#pragma unroll
    for (int di = 0; di < 2; ++di)
#pragma unroll
      for (int r = 0; r < 4; ++r) {
        int n = mi * 16 + g * 4 + r;
        if (n < 49)
          out[(tokbase + n) * 384 + h * 32 + di * 16 + q] = f2b(o[mi][di][r]);
      }
}

// ---------------------------------------------------------------- launch
extern "C" void kernel_launch(void* const* d_in, const int* in_sizes, int n_in,
                              void* d_out, int out_size, void* d_ws,
                              size_t ws_size, hipStream_t stream) {
  const float* x = (const float*)d_in[0];
  const float* n1g = (const float*)d_in[1];
  const float* n1b = (const float*)d_in[2];
  const float* qkvw = (const float*)d_in[3];
  const float* qkvb = (const float*)d_in[4];
  const float* projw = (const float*)d_in[5];
  const float* projb = (const float*)d_in[6];
  const float* rpb = (const float*)d_in[7];
  const float* n2g = (const float*)d_in[8];
  const float* n2b = (const float*)d_in[9];
  const float* fc1w = (const float*)d_in[10];
  const float* fc1b = (const float*)d_in[11];
  const float* fc2w = (const float*)d_in[12];
  const float* fc2b = (const float*)d_in[13];
  float* out = (float*)d_out;

  char* ws = (char*)d_ws;
  short* w_qkvT = (short*)(ws + 0);
  short* w_projT = (short*)(ws + 884736);
  short* w_fc1T = (short*)(ws + 1179648);
  short* w_fc2T = (short*)(ws + 2359296);
  float* w_qb = (float*)(ws + 3538944);
  const size_t o_qkv = 3543552;
  short* qkvbuf = (short*)(ws + o_qkv);
  const size_t o_hwin = o_qkv + 462422016ull;
  short* hwin = (short*)(ws + o_hwin);
  const size_t o_fc1 = o_hwin + 154140672ull;

  int NC;
  size_t fc1_off = o_fc1;
  if (ws_size >= o_fc1 + 616562688ull) NC = 1;
  else if (ws_size >= o_fc1 + 308281344ull) NC = 2;
  else if (ws_size >= o_fc1 + 154140672ull) NC = 4;
  else { NC = 4; fc1_off = o_hwin; }
  short* fc1c = (short*)(ws + fc1_off);
  short* h2 = qkvbuf;

  const float qscale = 0.17677669529663687f;

  convT_k<<<(442368 + 255) / 256, 256, 0, stream>>>(qkvw, w_qkvT, 384, 1152, 384, qscale);
  convT_k<<<(147456 + 255) / 256, 256, 0, stream>>>(projw, w_projT, 384, 384, 0, 1.f);
  convT_k<<<(589824 + 255) / 256, 256, 0, stream>>>(fc1w, w_fc1T, 384, 1536, 0, 1.f);
  convT_k<<<(589824 + 255) / 256, 256, 0, stream>>>(fc2w, w_fc2T, 1536, 384, 0, 1.f);
  scale_bias_k<<<5, 256, 0, stream>>>(qkvb, w_qb, 1152, 384, qscale);

  ln1_k<<<50176, 256, 0, stream>>>(x, n1g, n1b, hwin);
  gemm_qkv_k<<<dim3(9, 1568), 256, 0, stream>>>(hwin, 384, w_qkvT, 384, w_qb,
                                                384, qkvbuf, 1152, nullptr,
                                                nullptr);
  attn_k<<<dim3(12, 4096), 64, 0, stream>>>(qkvbuf, rpb, hwin);
  gemm_proj_k<<<dim3(3, 1568), 256, 0, stream>>>(hwin, 384, w_projT, 384,
                                                 projb, 384, nullptr, 384, out,
                                                 x);
  ln2_k<<<50176, 256, 0, stream>>>(out, n2g, n2b, h2);
  const int CK = 1536 / NC;
  for (int c = 0; c < NC; ++c) {
    gemm_fc1_k<<<dim3(CK >> 7, 1568), 256, 0, stream>>>(
        h2, 384, w_fc1T + (size_t)c * CK * 384, 384, fc1b + c * CK, 384, fc1c,
        CK, nullptr, nullptr);
    gemm_fc2_k<<<dim3(3, 1568), 256, 0, stream>>>(
        fc1c, CK, w_fc2T + c * CK, 1536, (c == 0) ? fc2b : nullptr, CK,
        nullptr, 384, out, nullptr);
  }
}

// Round 3
// 2341.384 us; speedup vs baseline: 1.3365x; 1.2749x over previous
//
#include <hip/hip_runtime.h>
#include <hip/hip_bf16.h>

typedef short bf16x8 __attribute__((ext_vector_type(8)));
typedef float f32x4 __attribute__((ext_vector_type(4)));

typedef __attribute__((address_space(1))) void gvoid;
typedef __attribute__((address_space(3))) void lvoid;

__device__ __forceinline__ short f2b(float f) {
  __hip_bfloat16 h = __float2bfloat16(f);
  return __builtin_bit_cast(short, h);
}

__device__ __forceinline__ f32x4 mfma16(bf16x8 a, bf16x8 b, f32x4 c) {
  return __builtin_amdgcn_mfma_f32_16x16x32_bf16(a, b, c, 0, 0, 0);
}

__device__ __forceinline__ void gload16(const void* g, void* l) {
  __builtin_amdgcn_global_load_lds((const gvoid*)g, (lvoid*)l, 16, 0, 0);
}

// ---------------------------------------------------------------- weights
__global__ __launch_bounds__(256) void convT_k(const float* __restrict__ src,
                                               short* __restrict__ dst, int K,
                                               int N, int scale_cols,
                                               float scale) {
  int idx = blockIdx.x * 256 + threadIdx.x;
  if (idx >= N * K) return;
  int n = idx / K, k = idx % K;
  float v = src[(size_t)k * N + n];
  if (n < scale_cols) v *= scale;
  dst[idx] = f2b(v);
}

__global__ __launch_bounds__(256) void scale_bias_k(const float* __restrict__ src,
                                                    float* __restrict__ dst,
                                                    int n, int scale_cols,
                                                    float scale) {
  int i = blockIdx.x * 256 + threadIdx.x;
  if (i >= n) return;
  dst[i] = src[i] * (i < scale_cols ? scale : 1.f);
}

// ---------------------------------------------------------------- layernorm
template <bool GATHER>
__device__ __forceinline__ void ln_body(const float* __restrict__ x,
                                        const float* __restrict__ gw,
                                        const float* __restrict__ bw,
                                        short* __restrict__ out) {
  const int lane = threadIdx.x & 63;
  const int t = (blockIdx.x << 2) + (threadIdx.x >> 6);
  size_t srow;
  if (GATHER) {
    int bb = t / 12544, rm2 = t % 12544;
    int wi = rm2 / 49, nn = rm2 % 49;
    int wh = wi >> 4, ww = wi & 15;
    int ii = nn / 7, jj = nn % 7;
    int rr = wh * 7 + ii + 3; if (rr >= 112) rr -= 112;
    int cc = ww * 7 + jj + 3; if (cc >= 112) cc -= 112;
    srow = ((size_t)bb * 12544 + rr * 112 + cc) * 384;
  } else {
    srow = (size_t)t * 384;
  }
  const float2* src = (const float2*)(x + srow);
  const float2* g2 = (const float2*)gw;
  const float2* b2 = (const float2*)bw;
  float2 u[3];
  float s = 0.f, ss = 0.f;
#pragma unroll
  for (int k = 0; k < 3; ++k) {
    u[k] = src[lane + (k << 6)];
    s += u[k].x + u[k].y;
    ss += u[k].x * u[k].x + u[k].y * u[k].y;
  }
#pragma unroll
  for (int m = 1; m < 64; m <<= 1) {
    s += __shfl_xor(s, m, 64);
    ss += __shfl_xor(ss, m, 64);
  }
  const float mean = s * (1.f / 384.f);
  const float var = ss * (1.f / 384.f) - mean * mean;
  const float rstd = rsqrtf(var + 1e-5f);
  unsigned* o = (unsigned*)(out + (size_t)t * 384);
#pragma unroll
  for (int k = 0; k < 3; ++k) {
    int c = lane + (k << 6);
    float2 gv = g2[c], bv = b2[c];
    unsigned lo = (unsigned short)f2b((u[k].x - mean) * rstd * gv.x + bv.x);
    unsigned hi = (unsigned short)f2b((u[k].y - mean) * rstd * gv.y + bv.y);
    o[c] = lo | (hi << 16);
  }
}

__global__ __launch_bounds__(256) void ln1_k(const float* __restrict__ x,
                                             const float* __restrict__ gw,
                                             const float* __restrict__ bw,
                                             short* __restrict__ out) {
  ln_body<true>(x, gw, bw, out);
}
__global__ __launch_bounds__(256) void ln2_k(const float* __restrict__ x,
                                             const float* __restrict__ gw,
                                             const float* __restrict__ bw,
                                             short* __restrict__ out) {
  ln_body<false>(x, gw, bw, out);
}

// ---------------------------------------------------------------- GEMM
// C[M,N] = A[M,K] * BT[N,K]^T + bias. 128x128 tile, BK=32, 4 waves (2x2).
// STATIC double-buffer (named LDS objects, compile-time identity) so the
// compiler's alias analysis can keep gload_lds (vmcnt) independent of the
// ds_reads (lgkmcnt) — a runtime-indexed As[cur] forces a conservative
// vmcnt(0) before every ds_read, serializing the pipeline (round-2 lesson).
// Requires nt = K/32 even (K = 384 or 768 here).
template <int EPI>
__device__ __forceinline__ void gemm_body(
    const short* __restrict__ A, int lda, const short* __restrict__ BT,
    int ldb, const float* __restrict__ bias, int K, short* __restrict__ outh,
    int ldo, float* __restrict__ outf, const float* __restrict__ resid) {
  __shared__ __align__(16) short As0[4096], Bs0[4096];
  __shared__ __align__(16) short As1[4096], Bs1[4096];
  const int tid = threadIdx.x;
  const int gx = gridDim.x;
  int lin = blockIdx.y * gx + blockIdx.x;
  const int cpx = (gx * gridDim.y) >> 3;
  lin = (lin & 7) * cpx + (lin >> 3);
  const int m0 = (lin / gx) << 7, n0 = (lin % gx) << 7;
  const int lane = tid & 63;
  const int wave = tid >> 6;
  const int wr = (wave >> 1) << 6, wc = (wave & 1) << 6;
  const int g = lane >> 4, q = lane & 15;
  const int loff = tid << 3;

  f32x4 acc[4][4];
#pragma unroll
  for (int i = 0; i < 4; ++i)
#pragma unroll
    for (int j = 0; j < 4; ++j) acc[i][j] = (f32x4){0.f, 0.f, 0.f, 0.f};

  const short* Ab = A + (size_t)(m0 + (tid >> 2)) * lda + ((tid & 3) << 3);
  const short* Ab2 = Ab + (size_t)64 * lda;
  const short* Bb = BT + (size_t)(n0 + (tid >> 2)) * ldb + ((tid & 3) << 3);
  const short* Bb2 = Bb + (size_t)64 * ldb;

#define STAGE(kt, dA, dB)                   \
  do {                                      \
    gload16(Ab + (kt), &dA[loff]);          \
    gload16(Ab2 + (kt), &dA[loff + 2048]);  \
    gload16(Bb + (kt), &dB[loff]);          \
    gload16(Bb2 + (kt), &dB[loff + 2048]);  \
  } while (0)

#define COMPUTE(SA, SB)                                               \
  do {                                                                \
    bf16x8 af[4], bfv[4];                                             \
    _Pragma("unroll") for (int mi = 0; mi < 4; ++mi)                  \
        af[mi] = *(const bf16x8*)&SA[(wr + mi * 16 + q) * 32 + g * 8];\
    _Pragma("unroll") for (int ni = 0; ni < 4; ++ni)                  \
        bfv[ni] = *(const bf16x8*)&SB[(wc + ni * 16 + q) * 32 + g * 8];\
    _Pragma("unroll") for (int mi = 0; mi < 4; ++mi)                  \
        _Pragma("unroll") for (int ni = 0; ni < 4; ++ni)              \
            acc[mi][ni] = mfma16(af[mi], bfv[ni], acc[mi][ni]);       \
  } while (0)

  const int nt = K >> 5;  // even for all call sites (12 or 24)
  STAGE(0, As0, Bs0);
  __syncthreads();
  for (int t = 0; t < nt; t += 2) {
    STAGE((t + 1) << 5, As1, Bs1);  // in flight across COMPUTE(As0)
    COMPUTE(As0, Bs0);
    __syncthreads();
    if (t + 2 < nt) STAGE((t + 2) << 5, As0, Bs0);
    COMPUTE(As1, Bs1);
    __syncthreads();
  }
#undef STAGE
#undef COMPUTE

  float bv[4];
#pragma unroll
  for (int ni = 0; ni < 4; ++ni)
    bv[ni] = bias ? bias[n0 + wc + ni * 16 + q] : 0.f;

#pragma unroll
  for (int mi = 0; mi < 4; ++mi) {
#pragma unroll
    for (int r = 0; r < 4; ++r) {
      const int grow = m0 + wr + mi * 16 + g * 4 + r;
      size_t orow;
      if constexpr (EPI == 2) {
        int bb = grow / 12544, rm2 = grow % 12544;
        int wi = rm2 / 49, nn = rm2 % 49;
        int wh = wi >> 4, ww = wi & 15;
        int ii = nn / 7, jj = nn % 7;
        int rr = wh * 7 + ii + 3; if (rr >= 112) rr -= 112;
        int cc = ww * 7 + jj + 3; if (cc >= 112) cc -= 112;
        orow = ((size_t)bb * 12544 + rr * 112 + cc) * 384;
      } else {
        orow = (size_t)grow * (size_t)ldo;
      }
#pragma unroll
      for (int ni = 0; ni < 4; ++ni) {
        const int gcol = n0 + wc + ni * 16 + q;
        float v = acc[mi][ni][r] + bv[ni];
        if constexpr (EPI == 0) {
          outh[orow + gcol] = f2b(v);
        } else if constexpr (EPI == 1) {
          v = 0.5f * v * (1.f + erff(v * 0.70710678118f));
          outh[orow + gcol] = f2b(v);
        } else if constexpr (EPI == 2) {
          outf[orow + gcol] = resid[orow + gcol] + v;
        } else {
          outf[orow + gcol] += v;
        }
      }
    }
  }
}

#define GEMM_WRAP(NAME, EPI)                                                   \
  __global__ __launch_bounds__(256) void NAME(                                 \
      const short* __restrict__ A, int lda, const short* __restrict__ BT,      \
      int ldb, const float* __restrict__ bias, int K,                          \
      short* __restrict__ outh, int ldo, float* __restrict__ outf,             \
      const float* __restrict__ resid) {                                       \
    gemm_body<EPI>(A, lda, BT, ldb, bias, K, outh, ldo, outf, resid);          \
  }
GEMM_WRAP(gemm_qkv_k, 0)
GEMM_WRAP(gemm_fc1_k, 1)
GEMM_WRAP(gemm_proj_k, 2)
GEMM_WRAP(gemm_fc2_k, 3)

// ---------------------------------------------------------------- attention
#define SW(row, sidx) ((sidx) ^ (((row)&7) << 3))

__global__ __launch_bounds__(64) void attn_k(const short* __restrict__ qkv,
                                             const float* __restrict__ rpb,
                                             short* __restrict__ out) {
  __shared__ __align__(16) short P[64 * 64];
  __shared__ __align__(16) short Vt[32 * 64];
  const int lane = threadIdx.x;
  const int g = lane >> 4, q = lane & 15;
  const int h = blockIdx.x;
  const int win = blockIdx.y;
  const int wh = (win >> 4) & 15, ww = win & 15;
  const size_t tokbase = (size_t)win * 49;
  const bf16x8 zero8 = {0, 0, 0, 0, 0, 0, 0, 0};

  bf16x8 qf[4], kf[4];
#pragma unroll
  for (int t = 0; t < 4; ++t) {
    int r = t * 16 + q;
    bool ok = r < 49;
    size_t off = (tokbase + (ok ? r : 0)) * 1152 + h * 32 + g * 8;
    bf16x8 a = *(const bf16x8*)(qkv + off);
    bf16x8 b = *(const bf16x8*)(qkv + off + 384);
    qf[t] = ok ? a : zero8;
    kf[t] = ok ? b : zero8;
  }
  f32x4 s[4][4];
#pragma unroll
  for (int mi = 0; mi < 4; ++mi)
#pragma unroll
    for (int ni = 0; ni < 4; ++ni)
      s[mi][ni] = mfma16(qf[mi], kf[ni], (f32x4){0.f, 0.f, 0.f, 0.f});

#pragma unroll
  for (int p = 0; p < 4; ++p) {
    int r = (p << 4) + (lane >> 2);
    int dch = (lane & 3) << 3;
    bf16x8 vv = zero8;
    if (r < 49)
      vv = *(const bf16x8*)(qkv + (tokbase + r) * 1152 + 768 + h * 32 + dch);
#pragma unroll
    for (int e = 0; e < 8; ++e) {
      int d = dch + e;
      Vt[SW(d, d * 64 + r)] = vv[e];
    }
  }

  int m4[4], i2[4], j2[4], creg[4];
#pragma unroll
  for (int ni = 0; ni < 4; ++ni) {
    m4[ni] = ni * 16 + q;
    int mc = m4[ni] < 49 ? m4[ni] : 48;
    i2[ni] = mc / 7;
    j2[ni] = mc % 7;
    int rr = wh * 7 + i2[ni], cc = ww * 7 + j2[ni];
    creg[ni] = ((rr >= 105) + (rr >= 109)) * 3 + (cc >= 105) + (cc >= 109);
  }
#pragma unroll
  for (int mi = 0; mi < 4; ++mi) {
#pragma unroll
    for (int r = 0; r < 4; ++r) {
      int n = mi * 16 + g * 4 + r;
      int nc = n < 49 ? n : 48;
      int i1 = nc / 7, j1 = nc % 7;
      int rr = wh * 7 + i1, cc = ww * 7 + j1;
      int rreg = ((rr >= 105) + (rr >= 109)) * 3 + (cc >= 105) + (cc >= 109);
#pragma unroll
      for (int ni = 0; ni < 4; ++ni) {
        float sv = s[mi][ni][r];
        sv += rpb[(size_t)((i1 - i2[ni] + 6) * 13 + (j1 - j2[ni] + 6)) * 12 + h];
        if (rreg != creg[ni]) sv -= 100.f;
        if (m4[ni] >= 49) sv = -1e30f;
        s[mi][ni][r] = sv;
      }
    }
  }
#pragma unroll
  for (int mi = 0; mi < 4; ++mi) {
#pragma unroll
    for (int r = 0; r < 4; ++r) {
      float mx = s[mi][0][r];
#pragma unroll
      for (int ni = 1; ni < 4; ++ni) mx = fmaxf(mx, s[mi][ni][r]);
#pragma unroll
      for (int m = 1; m < 16; m <<= 1) mx = fmaxf(mx, __shfl_xor(mx, m, 64));
      float sm = 0.f;
#pragma unroll
      for (int ni = 0; ni < 4; ++ni) {
        float e = __expf(s[mi][ni][r] - mx);
        s[mi][ni][r] = e;
        sm += e;
      }
#pragma unroll
      for (int m = 1; m < 16; m <<= 1) sm += __shfl_xor(sm, m, 64);
      float rinv = 1.f / sm;
      int row = mi * 16 + g * 4 + r;
#pragma unroll
      for (int ni = 0; ni < 4; ++ni)
        P[SW(row, row * 64 + ni * 16 + q)] = f2b(s[mi][ni][r] * rinv);
    }
  }
  __syncthreads();

  f32x4 o[4][2];
#pragma unroll
  for (int mi = 0; mi < 4; ++mi)
#pragma unroll
    for (int di = 0; di < 2; ++di) o[mi][di] = (f32x4){0.f, 0.f, 0.f, 0.f};
#pragma unroll
  for (int kt = 0; kt < 2; ++kt) {
    bf16x8 pa[4], vb[2];
#pragma unroll
    for (int mi = 0; mi < 4; ++mi) {
      int row = mi * 16 + q;
      pa[mi] = *(const bf16x8*)&P[SW(row, row * 64 + kt * 32 + g * 8)];
    }
#pragma unroll
    for (int di = 0; di < 2; ++di) {
      int row = di * 16 + q;
      vb[di] = *(const bf16x8*)&Vt[SW(row, row * 64 + kt * 32 + g * 8)];
    }
#pragma unroll
    for (int mi = 0; mi < 4; ++mi)
#pragma unroll
      for (int di = 0; di < 2; ++di)
        o[mi][di] = mfma16(pa[mi], vb[di], o[mi][di]);
  }
#pragma unroll
  for (int mi = 0; mi < 4; ++mi)
#pragma unroll
    for (int di = 0; di < 2; ++di)
#pragma unroll
      for (int r = 0; r < 4; ++r) {
        int n = mi * 16 + g * 4 + r;
        if (n < 49)
          out[(tokbase + n) * 384 + h * 32 + di * 16 + q] = f2b(o[mi][di][r]);
      }
}

// ---------------------------------------------------------------- launch
extern "C" void kernel_launch(void* const* d_in, const int* in_sizes, int n_in,
                              void* d_out, int out_size, void* d_ws,
                              size_t ws_size, hipStream_t stream) {
  const float* x = (const float*)d_in[0];
  const float* n1g = (const float*)d_in[1];
  const float* n1b = (const float*)d_in[2];
  const float* qkvw = (const float*)d_in[3];
  const float* qkvb = (const float*)d_in[4];
  const float* projw = (const float*)d_in[5];
  const float* projb = (const float*)d_in[6];
  const float* rpb = (const float*)d_in[7];
  const float* n2g = (const float*)d_in[8];
  const float* n2b = (const float*)d_in[9];
  const float* fc1w = (const float*)d_in[10];
  const float* fc1b = (const float*)d_in[11];
  const float* fc2w = (const float*)d_in[12];
  const float* fc2b = (const float*)d_in[13];
  float* out = (float*)d_out;

  char* ws = (char*)d_ws;
  short* w_qkvT = (short*)(ws + 0);
  short* w_projT = (short*)(ws + 884736);
  short* w_fc1T = (short*)(ws + 1179648);
  short* w_fc2T = (short*)(ws + 2359296);
  float* w_qb = (float*)(ws + 3538944);
  const size_t o_qkv = 3543552;
  short* qkvbuf = (short*)(ws + o_qkv);
  const size_t o_hwin = o_qkv + 462422016ull;
  short* hwin = (short*)(ws + o_hwin);
  const size_t o_fc1 = o_hwin + 154140672ull;

  int NC;
  size_t fc1_off = o_fc1;
  if (ws_size >= o_fc1 + 616562688ull) NC = 1;
  else if (ws_size >= o_fc1 + 308281344ull) NC = 2;
  else if (ws_size >= o_fc1 + 154140672ull) NC = 4;
  else { NC = 4; fc1_off = o_hwin; }
  short* fc1c = (short*)(ws + fc1_off);
  short* h2 = qkvbuf;

  const float qscale = 0.17677669529663687f;

  convT_k<<<(442368 + 255) / 256, 256, 0, stream>>>(qkvw, w_qkvT, 384, 1152, 384, qscale);
  convT_k<<<(147456 + 255) / 256, 256, 0, stream>>>(projw, w_projT, 384, 384, 0, 1.f);
  convT_k<<<(589824 + 255) / 256, 256, 0, stream>>>(fc1w, w_fc1T, 384, 1536, 0, 1.f);
  convT_k<<<(589824 + 255) / 256, 256, 0, stream>>>(fc2w, w_fc2T, 1536, 384, 0, 1.f);
  scale_bias_k<<<5, 256, 0, stream>>>(qkvb, w_qb, 1152, 384, qscale);

  ln1_k<<<50176, 256, 0, stream>>>(x, n1g, n1b, hwin);
  gemm_qkv_k<<<dim3(9, 1568), 256, 0, stream>>>(hwin, 384, w_qkvT, 384, w_qb,
                                                384, qkvbuf, 1152, nullptr,
                                                nullptr);
  attn_k<<<dim3(12, 4096), 64, 0, stream>>>(qkvbuf, rpb, hwin);
  gemm_proj_k<<<dim3(3, 1568), 256, 0, stream>>>(hwin, 384, w_projT, 384,
                                                 projb, 384, nullptr, 384, out,
                                                 x);
  ln2_k<<<50176, 256, 0, stream>>>(out, n2g, n2b, h2);
  const int CK = 1536 / NC;
  for (int c = 0; c < NC; ++c) {
    gemm_fc1_k<<<dim3(CK >> 7, 1568), 256, 0, stream>>>(
        h2, 384, w_fc1T + (size_t)c * CK * 384, 384, fc1b + c * CK, 384, fc1c,
        CK, nullptr, nullptr);
    gemm_fc2_k<<<dim3(3, 1568), 256, 0, stream>>>(
        fc1c, CK, w_fc2T + c * CK, 1536, (c == 0) ? fc2b : nullptr, CK,
        nullptr, 384, out, nullptr);
  }
}

// Round 4
// 2158.761 us; speedup vs baseline: 1.4496x; 1.0846x over previous
//
#include <hip/hip_runtime.h>
#include <hip/hip_bf16.h>

typedef short bf16x8 __attribute__((ext_vector_type(8)));
typedef float f32x4 __attribute__((ext_vector_type(4)));
typedef float f32x16 __attribute__((ext_vector_type(16)));
typedef unsigned int u32x4 __attribute__((ext_vector_type(4)));

typedef __attribute__((address_space(1))) void gvoid;
typedef __attribute__((address_space(3))) void lvoid;

__device__ __forceinline__ short f2b(float f) {
  __hip_bfloat16 h = __float2bfloat16(f);
  return __builtin_bit_cast(short, h);
}

__device__ __forceinline__ f32x4 mfma16(bf16x8 a, bf16x8 b, f32x4 c) {
  return __builtin_amdgcn_mfma_f32_16x16x32_bf16(a, b, c, 0, 0, 0);
}

__device__ __forceinline__ f32x16 mfma32(bf16x8 a, bf16x8 b, f32x16 c) {
  return __builtin_amdgcn_mfma_f32_32x32x16_bf16(a, b, c, 0, 0, 0);
}

__device__ __forceinline__ unsigned cvtpk(float lo, float hi) {
  unsigned r;
  asm("v_cvt_pk_bf16_f32 %0, %1, %2" : "=v"(r) : "v"(lo), "v"(hi));
  return r;
}

__device__ __forceinline__ void gload16(const void* g, void* l) {
  __builtin_amdgcn_global_load_lds((const gvoid*)g, (lvoid*)l, 16, 0, 0);
}

// ---------------------------------------------------------------- weights
__global__ __launch_bounds__(256) void convT_k(const float* __restrict__ src,
                                               short* __restrict__ dst, int K,
                                               int N, int scale_cols,
                                               float scale) {
  int idx = blockIdx.x * 256 + threadIdx.x;
  if (idx >= N * K) return;
  int n = idx / K, k = idx % K;
  float v = src[(size_t)k * N + n];
  if (n < scale_cols) v *= scale;
  dst[idx] = f2b(v);
}

__global__ __launch_bounds__(256) void scale_bias_k(const float* __restrict__ src,
                                                    float* __restrict__ dst,
                                                    int n, int scale_cols,
                                                    float scale) {
  int i = blockIdx.x * 256 + threadIdx.x;
  if (i >= n) return;
  dst[i] = src[i] * (i < scale_cols ? scale : 1.f);
}

// Combined rel-pos bias + shift mask table: tbl[cls][h][key][query], f32.
// cls = (wh==15)*2 + (ww==15). key/query >= 49 -> -1e4 (softmax zero).
__global__ __launch_bounds__(256) void biasmask_k(const float* __restrict__ rpb,
                                                  float* __restrict__ tbl) {
  int idx = blockIdx.x * 256 + threadIdx.x;  // < 4*12*64*64
  int q = idx & 63, key = (idx >> 6) & 63;
  int hc = idx >> 12;  // cls*12 + h
  int h = hc % 12, cls = hc / 12;
  float v;
  if (q >= 49 || key >= 49) {
    v = -1e4f;
  } else {
    int i1 = q / 7, j1 = q % 7, i2 = key / 7, j2 = key % 7;
    v = rpb[(size_t)((i1 - i2 + 6) * 13 + (j1 - j2 + 6)) * 12 + h];
    int clsh = cls >> 1, clsw = cls & 1;
    int rq = (clsh ? 1 + (i1 >= 4) : 0) * 3 + (clsw ? 1 + (j1 >= 4) : 0);
    int rk = (clsh ? 1 + (i2 >= 4) : 0) * 3 + (clsw ? 1 + (j2 >= 4) : 0);
    if (rq != rk) v -= 100.f;
  }
  tbl[idx] = v;
}

// ---------------------------------------------------------------- layernorm
template <bool GATHER>
__device__ __forceinline__ void ln_body(const float* __restrict__ x,
                                        const float* __restrict__ gw,
                                        const float* __restrict__ bw,
                                        short* __restrict__ out) {
  const int lane = threadIdx.x & 63;
  const int t = (blockIdx.x << 2) + (threadIdx.x >> 6);
  size_t srow;
  if (GATHER) {
    int bb = t / 12544, rm2 = t % 12544;
    int wi = rm2 / 49, nn = rm2 % 49;
    int wh = wi >> 4, ww = wi & 15;
    int ii = nn / 7, jj = nn % 7;
    int rr = wh * 7 + ii + 3; if (rr >= 112) rr -= 112;
    int cc = ww * 7 + jj + 3; if (cc >= 112) cc -= 112;
    srow = ((size_t)bb * 12544 + rr * 112 + cc) * 384;
  } else {
    srow = (size_t)t * 384;
  }
  const float2* src = (const float2*)(x + srow);
  const float2* g2 = (const float2*)gw;
  const float2* b2 = (const float2*)bw;
  float2 u[3];
  float s = 0.f, ss = 0.f;
#pragma unroll
  for (int k = 0; k < 3; ++k) {
    u[k] = src[lane + (k << 6)];
    s += u[k].x + u[k].y;
    ss += u[k].x * u[k].x + u[k].y * u[k].y;
  }
#pragma unroll
  for (int m = 1; m < 64; m <<= 1) {
    s += __shfl_xor(s, m, 64);
    ss += __shfl_xor(ss, m, 64);
  }
  const float mean = s * (1.f / 384.f);
  const float var = ss * (1.f / 384.f) - mean * mean;
  const float rstd = rsqrtf(var + 1e-5f);
  unsigned* o = (unsigned*)(out + (size_t)t * 384);
#pragma unroll
  for (int k = 0; k < 3; ++k) {
    int c = lane + (k << 6);
    float2 gv = g2[c], bv = b2[c];
    unsigned lo = (unsigned short)f2b((u[k].x - mean) * rstd * gv.x + bv.x);
    unsigned hi = (unsigned short)f2b((u[k].y - mean) * rstd * gv.y + bv.y);
    o[c] = lo | (hi << 16);
  }
}

__global__ __launch_bounds__(256) void ln1_k(const float* __restrict__ x,
                                             const float* __restrict__ gw,
                                             const float* __restrict__ bw,
                                             short* __restrict__ out) {
  ln_body<true>(x, gw, bw, out);
}
__global__ __launch_bounds__(256) void ln2_k(const float* __restrict__ x,
                                             const float* __restrict__ gw,
                                             const float* __restrict__ bw,
                                             short* __restrict__ out) {
  ln_body<false>(x, gw, bw, out);
}

// ---------------------------------------------------------------- GEMM
// 128x128 tile, BK=32, 4 waves (2x2), STATIC double-buffer (named LDS
// objects so alias analysis keeps gload_lds independent of ds_reads).
template <int EPI>
__device__ __forceinline__ void gemm_body(
    const short* __restrict__ A, int lda, const short* __restrict__ BT,
    int ldb, const float* __restrict__ bias, int K, short* __restrict__ outh,
    int ldo, float* __restrict__ outf, const float* __restrict__ resid) {
  __shared__ __align__(16) short As0[4096], Bs0[4096];
  __shared__ __align__(16) short As1[4096], Bs1[4096];
  const int tid = threadIdx.x;
  const int gx = gridDim.x;
  int lin = blockIdx.y * gx + blockIdx.x;
  const int cpx = (gx * gridDim.y) >> 3;
  lin = (lin & 7) * cpx + (lin >> 3);
  const int m0 = (lin / gx) << 7, n0 = (lin % gx) << 7;
  const int lane = tid & 63;
  const int wave = tid >> 6;
  const int wr = (wave >> 1) << 6, wc = (wave & 1) << 6;
  const int g = lane >> 4, q = lane & 15;
  const int loff = tid << 3;

  f32x4 acc[4][4];
#pragma unroll
  for (int i = 0; i < 4; ++i)
#pragma unroll
    for (int j = 0; j < 4; ++j) acc[i][j] = (f32x4){0.f, 0.f, 0.f, 0.f};

  const short* Ab = A + (size_t)(m0 + (tid >> 2)) * lda + ((tid & 3) << 3);
  const short* Ab2 = Ab + (size_t)64 * lda;
  const short* Bb = BT + (size_t)(n0 + (tid >> 2)) * ldb + ((tid & 3) << 3);
  const short* Bb2 = Bb + (size_t)64 * ldb;

#define STAGE(kt, dA, dB)                   \
  do {                                      \
    gload16(Ab + (kt), &dA[loff]);          \
    gload16(Ab2 + (kt), &dA[loff + 2048]);  \
    gload16(Bb + (kt), &dB[loff]);          \
    gload16(Bb2 + (kt), &dB[loff + 2048]);  \
  } while (0)

#define COMPUTE(SA, SB)                                               \
  do {                                                                \
    bf16x8 af[4], bfv[4];                                             \
    _Pragma("unroll") for (int mi = 0; mi < 4; ++mi)                  \
        af[mi] = *(const bf16x8*)&SA[(wr + mi * 16 + q) * 32 + g * 8];\
    _Pragma("unroll") for (int ni = 0; ni < 4; ++ni)                  \
        bfv[ni] = *(const bf16x8*)&SB[(wc + ni * 16 + q) * 32 + g * 8];\
    _Pragma("unroll") for (int mi = 0; mi < 4; ++mi)                  \
        _Pragma("unroll") for (int ni = 0; ni < 4; ++ni)              \
            acc[mi][ni] = mfma16(af[mi], bfv[ni], acc[mi][ni]);       \
  } while (0)

  const int nt = K >> 5;  // even for all call sites
  STAGE(0, As0, Bs0);
  __syncthreads();
  for (int t = 0; t < nt; t += 2) {
    STAGE((t + 1) << 5, As1, Bs1);
    COMPUTE(As0, Bs0);
    __syncthreads();
    if (t + 2 < nt) STAGE((t + 2) << 5, As0, Bs0);
    COMPUTE(As1, Bs1);
    __syncthreads();
  }
#undef STAGE
#undef COMPUTE

  float bv[4];
#pragma unroll
  for (int ni = 0; ni < 4; ++ni)
    bv[ni] = bias ? bias[n0 + wc + ni * 16 + q] : 0.f;

#pragma unroll
  for (int mi = 0; mi < 4; ++mi) {
#pragma unroll
    for (int r = 0; r < 4; ++r) {
      const int grow = m0 + wr + mi * 16 + g * 4 + r;
      size_t orow;
      if constexpr (EPI == 2) {
        int bb = grow / 12544, rm2 = grow % 12544;
        int wi = rm2 / 49, nn = rm2 % 49;
        int wh = wi >> 4, ww = wi & 15;
        int ii = nn / 7, jj = nn % 7;
        int rr = wh * 7 + ii + 3; if (rr >= 112) rr -= 112;
        int cc = ww * 7 + jj + 3; if (cc >= 112) cc -= 112;
        orow = ((size_t)bb * 12544 + rr * 112 + cc) * 384;
      } else {
        orow = (size_t)grow * (size_t)ldo;
      }
#pragma unroll
      for (int ni = 0; ni < 4; ++ni) {
        const int gcol = n0 + wc + ni * 16 + q;
        float v = acc[mi][ni][r] + bv[ni];
        if constexpr (EPI == 0) {
          outh[orow + gcol] = f2b(v);
        } else if constexpr (EPI == 1) {
          v = 0.5f * v * (1.f + erff(v * 0.70710678118f));
          outh[orow + gcol] = f2b(v);
        } else if constexpr (EPI == 2) {
          outf[orow + gcol] = resid[orow + gcol] + v;
        } else {
          outf[orow + gcol] += v;
        }
      }
    }
  }
}

#define GEMM_WRAP(NAME, EPI)                                                   \
  __global__ __launch_bounds__(256) void NAME(                                 \
      const short* __restrict__ A, int lda, const short* __restrict__ BT,      \
      int ldb, const float* __restrict__ bias, int K,                          \
      short* __restrict__ outh, int ldo, float* __restrict__ outf,             \
      const float* __restrict__ resid) {                                       \
    gemm_body<EPI>(A, lda, BT, ldb, bias, K, outh, ldo, outf, resid);          \
  }
GEMM_WRAP(gemm_qkv_k, 0)
GEMM_WRAP(gemm_fc1_k, 1)
GEMM_WRAP(gemm_proj_k, 2)
GEMM_WRAP(gemm_fc2_k, 3)

// ---------------------------------------------------------------- attention
// One wave per (window, head), 4 waves/block, ZERO LDS.
// Swapped QK^T via mfma_32x32x16: S^T[key][query] = mfma(A=K, B=Q).
// C-layout (m74/m101): col = lane&31, row = (reg&3)+8*(reg>>2)+4*(lane>>5)
// -> each lane owns query col (lane&31), 32 of 64 keys in-reg; partner lane
// (^32) owns the other 32. Softmax = 31 in-lane ops + 1 shfl_xor(32).
// P stays in registers: cvt_pk to bf16 + quad exchange via shfl_xor(32)
// assembles the PV A-fragment (T12). O[query][d] = mfma(A=P, B=V^T), V^T
// frags loaded straight from global (L2-hot). Bias+mask from precomputed
// table (coalesced f32 loads). Q pre-scaled in folded weights.
__global__ __launch_bounds__(256) void attn_k(const short* __restrict__ qkv,
                                              const float* __restrict__ tbl,
                                              short* __restrict__ out) {
  const int lane = threadIdx.x & 63;
  const int task = blockIdx.x * 4 + (threadIdx.x >> 6);
  const int win = task / 12;
  const int h = task - win * 12;
  const int wh = (win >> 4) & 15, ww = win & 15;
  const int cls = ((wh == 15) ? 2 : 0) + ((ww == 15) ? 1 : 0);
  const int l31 = lane & 31, h5 = lane >> 5;
  const size_t tokbase = (size_t)win * 49;
  const short* base = qkv + tokbase * 1152 + h * 32;
  const bf16x8 zero8 = {0, 0, 0, 0, 0, 0, 0, 0};

  // K A-frags: kf[mi][s] = K[key=l31+32mi][d=16s+8h5+e]
  bf16x8 kf[2][2];
#pragma unroll
  for (int mi = 0; mi < 2; ++mi) {
    int row = l31 + 32 * mi;
#pragma unroll
    for (int s = 0; s < 2; ++s)
      kf[mi][s] = (row < 49)
                      ? *(const bf16x8*)(base + (size_t)row * 1152 + 384 +
                                         16 * s + 8 * h5)
                      : zero8;
  }
  // V^T B-frags: vf[kt][e] = V[key=16kt+8h5+e][d=l31]
  bf16x8 vf[4];
#pragma unroll
  for (int kt = 0; kt < 4; ++kt) {
#pragma unroll
    for (int e = 0; e < 8; ++e) {
      int key = 16 * kt + 8 * h5 + e;
      vf[kt][e] = (key < 49) ? base[(size_t)key * 1152 + 768 + l31] : (short)0;
    }
  }

  const float* tb = tbl + ((size_t)(cls * 12 + h) << 12);

#pragma unroll
  for (int ni = 0; ni < 2; ++ni) {
    // Q B-frags
    bf16x8 qf[2];
    int qrow = l31 + 32 * ni;
#pragma unroll
    for (int s = 0; s < 2; ++s)
      qf[s] = (qrow < 49)
                  ? *(const bf16x8*)(base + (size_t)qrow * 1152 + 16 * s +
                                     8 * h5)
                  : zero8;
    // S^T tiles
    f32x16 st[2];
#pragma unroll
    for (int mi = 0; mi < 2; ++mi) {
      st[mi] = mfma32(kf[mi][0], qf[0], (f32x16)(0.f));
      st[mi] = mfma32(kf[mi][1], qf[1], st[mi]);
    }
    // + bias/mask table (key<49 real, key>=49 -> -1e4)
#pragma unroll
    for (int mi = 0; mi < 2; ++mi)
#pragma unroll
      for (int r = 0; r < 16; ++r) {
        int koff = (r & 3) + 8 * (r >> 2) + 4 * h5;
        st[mi][r] += tb[(size_t)(32 * mi + koff) * 64 + 32 * ni + l31];
      }
    // softmax over 64 keys: 32 in-lane + partner via shfl_xor(32)
    float mx = st[0][0];
#pragma unroll
    for (int r = 1; r < 16; ++r) mx = fmaxf(mx, st[0][r]);
#pragma unroll
    for (int r = 0; r < 16; ++r) mx = fmaxf(mx, st[1][r]);
    mx = fmaxf(mx, __shfl_xor(mx, 32, 64));
    float sm = 0.f;
#pragma unroll
    for (int mi = 0; mi < 2; ++mi)
#pragma unroll
      for (int r = 0; r < 16; ++r) {
        float e = __expf(st[mi][r] - mx);
        st[mi][r] = e;
        sm += e;
      }
    sm += __shfl_xor(sm, 32, 64);
    const float rinv = 1.f / sm;
#pragma unroll
    for (int mi = 0; mi < 2; ++mi)
#pragma unroll
      for (int r = 0; r < 16; ++r) st[mi][r] *= rinv;

    // PV: assemble P A-frags (keys 16kt+8h5+0..7 for query l31) via
    // cvt_pk + quad exchange with partner lane (^32), then accumulate.
    f32x16 acc = (f32x16)(0.f);
#pragma unroll
    for (int kt = 0; kt < 4; ++kt) {
      const int mi = kt >> 1, b8 = (kt & 1) * 8;
      // quad j=2b (own keys 16b+4h5+0..3), j=2b+1 (own keys 16b+8+4h5+0..3)
      unsigned q0l = cvtpk(st[mi][b8 + 0], st[mi][b8 + 1]);
      unsigned q0h = cvtpk(st[mi][b8 + 2], st[mi][b8 + 3]);
      unsigned q1l = cvtpk(st[mi][b8 + 4], st[mi][b8 + 5]);
      unsigned q1h = cvtpk(st[mi][b8 + 6], st[mi][b8 + 7]);
      // h5=0 sends quad j=2b+1 (keys 16b+8..11), h5=1 sends j=2b (16b+4..7)
      unsigned sl = h5 ? q0l : q1l, sh = h5 ? q0h : q1h;
      unsigned kl = h5 ? q1l : q0l, kh = h5 ? q1h : q0h;
      unsigned rl = (unsigned)__shfl_xor((int)sl, 32, 64);
      unsigned rh = (unsigned)__shfl_xor((int)sh, 32, 64);
      u32x4 fr;
      fr[0] = h5 ? rl : kl;
      fr[1] = h5 ? rh : kh;
      fr[2] = h5 ? kl : rl;
      fr[3] = h5 ? kh : rh;
      acc = mfma32(__builtin_bit_cast(bf16x8, fr), vf[kt], acc);
    }
    // store O[query][d=l31]
#pragma unroll
    for (int r = 0; r < 16; ++r) {
      int query = 32 * ni + (r & 3) + 8 * (r >> 2) + 4 * h5;
      if (ni == 0 || query < 49)
        out[(tokbase + query) * 384 + h * 32 + l31] = f2b(acc[r]);
    }
  }
}

// ---------------------------------------------------------------- launch
extern "C" void kernel_launch(void* const* d_in, const int* in_sizes, int n_in,
                              void* d_out, int out_size, void* d_ws,
                              size_t ws_size, hipStream_t stream) {
  const float* x = (const float*)d_in[0];
  const float* n1g = (const float*)d_in[1];
  const float* n1b = (const float*)d_in[2];
  const float* qkvw = (const float*)d_in[3];
  const float* qkvb = (const float*)d_in[4];
  const float* projw = (const float*)d_in[5];
  const float* projb = (const float*)d_in[6];
  const float* rpb = (const float*)d_in[7];
  const float* n2g = (const float*)d_in[8];
  const float* n2b = (const float*)d_in[9];
  const float* fc1w = (const float*)d_in[10];
  const float* fc1b = (const float*)d_in[11];
  const float* fc2w = (const float*)d_in[12];
  const float* fc2b = (const float*)d_in[13];
  float* out = (float*)d_out;

  char* ws = (char*)d_ws;
  short* w_qkvT = (short*)(ws + 0);            // 884736 B
  short* w_projT = (short*)(ws + 884736);      // 294912 B
  short* w_fc1T = (short*)(ws + 1179648);      // 1179648 B
  short* w_fc2T = (short*)(ws + 2359296);      // 1179648 B
  float* w_qb = (float*)(ws + 3538944);        // 4608 B
  float* tbl = (float*)(ws + 3543552);         // 4*12*64*64*4 = 786432 B
  const size_t o_qkv = 4329984;
  short* qkvbuf = (short*)(ws + o_qkv);        // 462422016 B
  const size_t o_hwin = o_qkv + 462422016ull;  // 466752000
  short* hwin = (short*)(ws + o_hwin);         // 154140672 B
  const size_t o_fc1 = o_hwin + 154140672ull;  // 620892672

  int NC;
  size_t fc1_off = o_fc1;
  if (ws_size >= o_fc1 + 616562688ull) NC = 1;
  else if (ws_size >= o_fc1 + 308281344ull) NC = 2;
  else if (ws_size >= o_fc1 + 154140672ull) NC = 4;
  else { NC = 4; fc1_off = o_hwin; }
  short* fc1c = (short*)(ws + fc1_off);
  short* h2 = qkvbuf;

  const float qscale = 0.17677669529663687f;

  convT_k<<<(442368 + 255) / 256, 256, 0, stream>>>(qkvw, w_qkvT, 384, 1152, 384, qscale);
  convT_k<<<(147456 + 255) / 256, 256, 0, stream>>>(projw, w_projT, 384, 384, 0, 1.f);
  convT_k<<<(589824 + 255) / 256, 256, 0, stream>>>(fc1w, w_fc1T, 384, 1536, 0, 1.f);
  convT_k<<<(589824 + 255) / 256, 256, 0, stream>>>(fc2w, w_fc2T, 1536, 384, 0, 1.f);
  scale_bias_k<<<5, 256, 0, stream>>>(qkvb, w_qb, 1152, 384, qscale);
  biasmask_k<<<768, 256, 0, stream>>>(rpb, tbl);

  ln1_k<<<50176, 256, 0, stream>>>(x, n1g, n1b, hwin);
  gemm_qkv_k<<<dim3(9, 1568), 256, 0, stream>>>(hwin, 384, w_qkvT, 384, w_qb,
                                                384, qkvbuf, 1152, nullptr,
                                                nullptr);
  attn_k<<<12288, 256, 0, stream>>>(qkvbuf, tbl, hwin);
  gemm_proj_k<<<dim3(3, 1568), 256, 0, stream>>>(hwin, 384, w_projT, 384,
                                                 projb, 384, nullptr, 384, out,
                                                 x);
  ln2_k<<<50176, 256, 0, stream>>>(out, n2g, n2b, h2);
  const int CK = 1536 / NC;
  for (int c = 0; c < NC; ++c) {
    gemm_fc1_k<<<dim3(CK >> 7, 1568), 256, 0, stream>>>(
        h2, 384, w_fc1T + (size_t)c * CK * 384, 384, fc1b + c * CK, 384, fc1c,
        CK, nullptr, nullptr);
    gemm_fc2_k<<<dim3(3, 1568), 256, 0, stream>>>(
        fc1c, CK, w_fc2T + c * CK, 1536, (c == 0) ? fc2b : nullptr, CK,
        nullptr, 384, out, nullptr);
  }
}